// Round 1
// baseline (83.609 us; speedup 1.0000x reference)
//
#include <hip/hip_runtime.h>
#include <math.h>

#define NPART 2048
#define NDIM  3
#define IPB   16    // output particles per block
#define SPLIT 16    // j-split (threads cooperating per output particle)
#define BLOCK (IPB * SPLIT)

// Each block: one batch slice of 16 particles. Full position set staged in LDS
// (3 planar arrays -> conflict-free broadcast reads with interleaved j).
__global__ __launch_bounds__(BLOCK, 4)
void backflow_kernel(const float* __restrict__ x, float* __restrict__ out,
                     float L, float invL) {
    __shared__ float xs[NPART];
    __shared__ float ys[NPART];
    __shared__ float zs[NPART];

    const int tid   = threadIdx.x;
    const int blk   = blockIdx.x;
    const int b     = blk >> 7;            // / (2048/16)
    const int ibase = (blk & 127) * IPB;
    const float* xb = x + b * (NPART * NDIM);

    // Stage + periodic wrap: v - L*floor(v/L)
    for (int e = tid; e < NPART * NDIM; e += BLOCK) {
        float v = xb[e];
        v = v - L * floorf(v * invL);
        int p = e / 3;
        int c = e - 3 * p;
        if      (c == 0) xs[p] = v;
        else if (c == 1) ys[p] = v;
        else             zs[p] = v;
    }
    __syncthreads();

    const int sub = tid & (SPLIT - 1);
    const int ii  = tid >> 4;
    const int i   = ibase + ii;

    const float xi = xs[i];
    const float yi = ys[i];
    const float zi = zs[i];

    float ax = 0.0f, ay = 0.0f, az = 0.0f;

    #pragma unroll 4
    for (int k = 0; k < NPART / SPLIT; ++k) {
        const int j = sub + k * SPLIT;     // interleaved: wave reads 16 banks, 4-lane broadcast
        float dx = xi - xs[j];
        float dy = yi - ys[j];
        float dz = zi - zs[j];
        // minimum image: dx - L*rint(dx/L)
        dx = fmaf(-L, rintf(dx * invL), dx);
        dy = fmaf(-L, rintf(dy * invL), dy);
        dz = fmaf(-L, rintf(dz * invL), dz);
        float d2 = fmaf(dx, dx, fmaf(dy, dy, dz * dz));
        // fr = 0.5*(exp(-(2.6/d)^5) - 1); self-pair: d2=0 -> rinv=inf -> exp(-inf)=0,
        // fr=-0.5, and fr*0 = 0 -> correct zero contribution, no NaN.
        float rinv = rsqrtf(d2);
        float t  = 2.6f * rinv;
        float t2 = t * t;
        float t5 = t2 * t2 * t;
        float fr = fmaf(0.5f, __expf(-t5), -0.5f);
        ax = fmaf(fr, dx, ax);
        ay = fmaf(fr, dy, ay);
        az = fmaf(fr, dz, az);
    }

    // reduce across the 16-lane j-split group (in-wave, contiguous lanes)
    #pragma unroll
    for (int off = 8; off >= 1; off >>= 1) {
        ax += __shfl_xor(ax, off);
        ay += __shfl_xor(ay, off);
        az += __shfl_xor(az, off);
    }

    if (sub == 0) {
        float* o = out + (b * NPART + i) * NDIM;
        o[0] = xi + ax;
        o[1] = yi + ay;
        o[2] = zi + az;
    }
}

extern "C" void kernel_launch(void* const* d_in, const int* in_sizes, int n_in,
                              void* d_out, int out_size, void* d_ws, size_t ws_size,
                              hipStream_t stream) {
    (void)in_sizes; (void)n_in; (void)d_ws; (void)ws_size; (void)out_size;
    const float* x = (const float*)d_in[0];
    float* out     = (float*)d_out;

    const double Ld = cbrt(2048.0 / 0.016355);   // matches reference float64 L
    const float  L    = (float)Ld;
    const float  invL = (float)(1.0 / Ld);

    const int nblocks = (8 * NPART) / IPB;       // 1024
    backflow_kernel<<<nblocks, BLOCK, 0, stream>>>(x, out, L, invL);
}

// Round 3
// 72.438 us; speedup vs baseline: 1.1542x; 1.1542x over previous
//
#include <hip/hip_runtime.h>
#include <math.h>

#define NPART 2048
#define IPB   16     // output particles per block
#define SPLIT 32     // j-split (threads cooperating per output particle)
#define BLOCK (IPB * SPLIT)   // 512

#if __has_builtin(__builtin_amdgcn_rsqf)
#define RSQF(x) __builtin_amdgcn_rsqf(x)
#else
#define RSQF(x) rsqrtf(x)
#endif
#if __has_builtin(__builtin_amdgcn_exp2f)
#define EXP2F(x) __builtin_amdgcn_exp2f(x)
#else
#define EXP2F(x) exp2f(x)
#endif

// Scaled-coordinate backflow: work in u = x/L in [0,1).
//   min-image: du -= rint(du)                    (3 ops/dim)
//   fr = 0.5*(exp2(K * (1/du)^5) - 1),  K = -log2(e) * (2.6/L)^5
//   out = L * (u_i + sum_j fr * du)
// Self-pair: du=0 -> d2=0 -> rsq=+inf -> K*inf=-inf -> exp2=0 -> fr=-0.5,
// fr*0 = 0 contribution. No NaN path.
__global__ __launch_bounds__(BLOCK, 8)
void backflow_kernel(const float* __restrict__ x, float* __restrict__ out,
                     float L, float invL, float K) {
    __shared__ float4 ps[NPART];   // 32 KB: scaled positions (x,y,z,0)

    const int tid   = threadIdx.x;
    const int blk   = blockIdx.x;
    const int b     = blk >> 7;            // / (2048/IPB)
    const int ibase = (blk & 127) * IPB;
    const float* xb = x + b * (NPART * 3);

    // Stage: wrap+scale u = frac(x * invL). 4 iters/thread, tiny data (L2-hot).
    for (int p = tid; p < NPART; p += BLOCK) {
        float ux = xb[3 * p + 0] * invL;
        float uy = xb[3 * p + 1] * invL;
        float uz = xb[3 * p + 2] * invL;
        ux -= floorf(ux);
        uy -= floorf(uy);
        uz -= floorf(uz);
        ps[p] = make_float4(ux, uy, uz, 0.0f);
    }
    __syncthreads();

    const int sub = tid & (SPLIT - 1);     // 0..31
    const int ii  = tid >> 5;              // 0..15
    const int i   = ibase + ii;

    const float4 pi = ps[i];
    const float uxi = pi.x, uyi = pi.y, uzi = pi.z;

    float ax = 0.0f, ay = 0.0f, az = 0.0f;

    #pragma unroll 4
    for (int k = 0; k < NPART / SPLIT; ++k) {
        const int j = sub + (k << 5);
        const float4 pj = ps[j];           // ds_read_b128, conflict-free
        float dx = uxi - pj.x;
        float dy = uyi - pj.y;
        float dz = uzi - pj.z;
        dx -= rintf(dx);                   // min image in scaled units
        dy -= rintf(dy);
        dz -= rintf(dz);
        float d2  = fmaf(dx, dx, fmaf(dy, dy, dz * dz));
        float ri  = RSQF(d2);              // 1/|du|
        float ri2 = ri * ri;
        float ri4 = ri2 * ri2;
        float e   = EXP2F((K * ri4) * ri); // exp2(K * ri^5)
        float fr  = fmaf(0.5f, e, -0.5f);
        ax = fmaf(fr, dx, ax);
        ay = fmaf(fr, dy, ay);
        az = fmaf(fr, dz, az);
    }

    // reduce across the 32-lane j-split group (within wave halves)
    #pragma unroll
    for (int off = 16; off >= 1; off >>= 1) {
        ax += __shfl_xor(ax, off);
        ay += __shfl_xor(ay, off);
        az += __shfl_xor(az, off);
    }

    if (sub == 0) {
        float* o = out + (b * NPART + i) * 3;
        o[0] = L * (uxi + ax);
        o[1] = L * (uyi + ay);
        o[2] = L * (uzi + az);
    }
}

extern "C" void kernel_launch(void* const* d_in, const int* in_sizes, int n_in,
                              void* d_out, int out_size, void* d_ws, size_t ws_size,
                              hipStream_t stream) {
    (void)in_sizes; (void)n_in; (void)d_ws; (void)ws_size; (void)out_size;
    const float* x = (const float*)d_in[0];
    float* out     = (float*)d_out;

    const double Ld   = cbrt(2048.0 / 0.016355);      // reference box length
    const double t    = 2.6 / Ld;
    const double Kd   = -(t * t * t * t * t) * 1.4426950408889634;  // -log2(e)*(2.6/L)^5
    const float  L    = (float)Ld;
    const float  invL = (float)(1.0 / Ld);
    const float  K    = (float)Kd;

    const int nblocks = (8 * NPART) / IPB;            // 1024
    backflow_kernel<<<nblocks, BLOCK, 0, stream>>>(x, out, L, invL, K);
}